// Round 1
// baseline (1943.826 us; speedup 1.0000x reference)
//
#include <hip/hip_runtime.h>

// ---------------------------------------------------------------------------
// Graph-conv LSTM encoder, B=4 T=12 N=4096 F=32, NG=14 gates.
// R3: fused GEMM+gates. Each block owns a 64-row tile for FULL K=4096
// (8 waves = 2 K-halves x 4 row-groups, LDS reduce + transpose), then runs
// the gate math in the epilogue. No split-K atomics, no Y buffers, no
// separate gate kernels: 2 dispatches per timestep. B panel reg-staged with
// issue-early/write-late prefetch (1 block/CU, so ILP must hide latency).
// m bf16 panel double-buffered by t parity (kernel2 reads m(t), writes m(t+1)).
// ---------------------------------------------------------------------------

typedef __bf16 bf16_t;
typedef __bf16 bf16x8 __attribute__((ext_vector_type(8)));
typedef float  f32x4  __attribute__((ext_vector_type(4)));

#define DI __device__ __forceinline__

#define BB 4
#define TT 12
#define NN 4096
#define FF 32

DI float sigm(float x)  { return __builtin_amdgcn_rcpf(1.f + __expf(-x)); }
DI float tanh_f(float x){ float e = __expf(2.f * x); return 1.f - 2.f * __builtin_amdgcn_rcpf(e + 1.f); }

// ---------------- adj fp32 -> bf16 (8 elements / thread) --------------------
__global__ __launch_bounds__(256) void conv_adj_k(const float* __restrict__ a,
                                                  bf16_t* __restrict__ o) {
    size_t i = ((size_t)blockIdx.x * 256 + threadIdx.x) * 8;
    float4 v0 = *(const float4*)(a + i);
    float4 v1 = *(const float4*)(a + i + 4);
    union { uint4 u; bf16_t h[8]; } t;
    t.h[0] = (bf16_t)v0.x; t.h[1] = (bf16_t)v0.y; t.h[2] = (bf16_t)v0.z; t.h[3] = (bf16_t)v0.w;
    t.h[4] = (bf16_t)v1.x; t.h[5] = (bf16_t)v1.y; t.h[6] = (bf16_t)v1.z; t.h[7] = (bf16_t)v1.w;
    *(uint4*)(o + i) = t.u;
}

// ---------------- x [B,T,N,F] fp32 -> xT [B, T*F, N] bf16 -------------------
__global__ __launch_bounds__(256) void xpose_k(const float* __restrict__ x,
                                               bf16_t* __restrict__ xT) {
    const int b = blockIdx.z, t = blockIdx.y, n0 = blockIdx.x * 64;
    const int tid = threadIdx.x;
    __shared__ float tile[64][33];
    const float* src = x + (((size_t)(b * TT + t)) * NN + n0) * FF;
#pragma unroll
    for (int rr = 0; rr < 2; ++rr) {
        int idx = rr * 256 + tid;
        int row = idx >> 3, seg = idx & 7;
        float4 v = *(const float4*)(src + row * FF + seg * 4);
        tile[row][seg * 4 + 0] = v.x; tile[row][seg * 4 + 1] = v.y;
        tile[row][seg * 4 + 2] = v.z; tile[row][seg * 4 + 3] = v.w;
    }
    __syncthreads();
    const int f = tid >> 3, seg = tid & 7;
    union { uint4 u; bf16_t h[8]; } o;
#pragma unroll
    for (int j = 0; j < 8; ++j) o.h[j] = (bf16_t)tile[seg * 8 + j][f];
    *(uint4*)&xT[((size_t)(b * 384 + t * FF + f)) * NN + n0 + seg * 8] = o.u;
}

// ---------------- W [14,32,64] fp32 -> MFMA B-fragments bf16 ----------------
__global__ __launch_bounds__(256) void make_wfrag_k(const float* __restrict__ W,
                                                    bf16_t* __restrict__ Wf) {
    const int g = blockIdx.x, tid = threadIdx.x;
    const int ct = tid >> 6, lane = tid & 63;
    const int k0 = (lane >> 4) * 8, col = ct * 16 + (lane & 15);
    union { uint4 u; bf16_t h[8]; } t;
#pragma unroll
    for (int j = 0; j < 8; ++j) t.h[j] = (bf16_t)W[(g * 32 + k0 + j) * 64 + col];
    *(uint4*)&Wf[((g * 4 + ct) * 64 + lane) * 8] = t.u;
}

// ---------------- init: h=1 (bf16), m slot0=1 (bf16), c=m=1 (fp32) ----------
__global__ __launch_bounds__(256) void init_k(bf16_t* h_bf, bf16_t* m0,
                                              float* c, float* m) {
    const int idx = blockIdx.x * 256 + threadIdx.x;   // 524288 = B*N*32
    h_bf[idx] = (bf16_t)1.f;
    m0[idx]   = (bf16_t)1.f;
    c[idx] = 1.f;
    m[idx] = 1.f;
}

// ---------------- fused GEMM + gates --------------------------------------
// Grid (64, B), 512 thr = 8 waves. Wave = (row-group wr=wave&3, K-half
// kh=wave>>2). Per wave: 16 rows x 64 cols x K=2048, 8 stages of 256 K.
// B panel (64 cols) staged per K-half in Vs[kh] (32 KB, XOR swizzle),
// reg-staged: issue loads for stage s+1 before MFMA(s), ds_write after the
// post-MFMA barrier. A streamed direct from global with 1-stage reg prefetch.
// Epilogue: both halves dump acc -> Yl LDS, waves 0-3 transpose-read the
// summed 64x64 Y tile as MFMA A-fragments and run the gate math.
// G1: Y = [adj@h | adj@x]   -> c_new, h_mid (bf16 [b][32][n])
// G2: Y = [adj@hmid | adj@m]-> m_new (fp32 + bf16 slot), h_new, hs out
template <bool ABF, bool G1>
__global__ __launch_bounds__(512, 2) void gg_k(
    const void* __restrict__ Ap,
    const bf16_t* __restrict__ p0, const bf16_t* __restrict__ p1,
    const bf16_t* __restrict__ Wf, const float* __restrict__ bias,
    float* __restrict__ cm, bf16_t* __restrict__ hmW,
    bf16_t* __restrict__ hb, float* __restrict__ hs, int t)
{
    constexpr int BS0 = 32;
    constexpr int BS1 = G1 ? 384 : 32;
    const int b = blockIdx.y, n0 = blockIdx.x * 64;
    const int tid = threadIdx.x;
    const int wave = tid >> 6, lane = tid & 63;
    const int mrow = lane & 15, quad = lane >> 4;
    const int wr = wave & 3, kh = wave >> 2;
    const int gtid = tid & 255;                 // tid within K-half group
    const int cw = gtid >> 5, ch = gtid & 31;   // staging col-word / chunk

    __shared__ __align__(16) bf16_t Vs[2][64 * 256];   // 64 KB: B panels
    __shared__ float Yl[2][64][68];                    // 34 KB: K-half partials
    __shared__ bf16_t t0T[32][64];                     // h_mid / m transpose
    __shared__ bf16_t t1T[32][64];                     // h transpose (G2)

    const int row = n0 + wr * 16 + mrow;
    const size_t arow = ((size_t)b << 24) + (size_t)row * NN;
    const f32x4 zero4 = {0.f, 0.f, 0.f, 0.f};
    f32x4 acc[4];
    acc[0] = zero4; acc[1] = zero4; acc[2] = zero4; acc[3] = zero4;

    // staging source rows + swizzled LDS offsets (8 x 16B chunks / thread)
    const bf16_t* srow[8];
    int loff[8];
#pragma unroll
    for (int rr = 0; rr < 8; ++rr) {
        const int c = rr * 8 + cw;
        const bf16_t* base = (c >= 32) ? p1 + ((size_t)b * BS1 + (c - 32)) * NN
                                       : p0 + ((size_t)b * BS0 + c) * NN;
        srow[rr] = base + kh * 2048 + ch * 8;
        loff[rr] = c * 256 + ((ch ^ (c & 7)) * 8);
    }
    const bf16_t* Abase  = (const bf16_t*)Ap + arow + kh * 2048 + quad * 8;
    const float*  AbaseF = (const float*)Ap + arow + kh * 2048 + quad * 8;

    uint4  brg[8];
    bf16x8 af[2][8];
    // ---- prologue: stage 0 ----
#pragma unroll
    for (int rr = 0; rr < 8; ++rr) brg[rr] = *(const uint4*)(srow[rr]);
    if constexpr (ABF) {
#pragma unroll
        for (int s = 0; s < 8; ++s) af[0][s] = *(const bf16x8*)(Abase + s * 32);
    }
#pragma unroll
    for (int rr = 0; rr < 8; ++rr) *(uint4*)&Vs[kh][loff[rr]] = brg[rr];
    __syncthreads();

    // ---- main loop: 8 stages x 256 K ----
#pragma unroll
    for (int stg = 0; stg < 8; ++stg) {
        const int cur = stg & 1, nxt = cur ^ 1;
        if (stg < 7) {   // issue next stage's loads (B first, then A)
#pragma unroll
            for (int rr = 0; rr < 8; ++rr)
                brg[rr] = *(const uint4*)(srow[rr] + (stg + 1) * 256);
            if constexpr (ABF) {
#pragma unroll
                for (int s = 0; s < 8; ++s)
                    af[nxt][s] = *(const bf16x8*)(Abase + (stg + 1) * 256 + s * 32);
            }
        }
        bf16x8 afs[8];
        if constexpr (ABF) {
#pragma unroll
            for (int s = 0; s < 8; ++s) afs[s] = af[cur][s];
        } else {
#pragma unroll
            for (int s = 0; s < 8; ++s) {
                float4 v0 = *(const float4*)(AbaseF + stg * 256 + s * 32);
                float4 v1 = *(const float4*)(AbaseF + stg * 256 + s * 32 + 4);
                afs[s][0] = (bf16_t)v0.x; afs[s][1] = (bf16_t)v0.y;
                afs[s][2] = (bf16_t)v0.z; afs[s][3] = (bf16_t)v0.w;
                afs[s][4] = (bf16_t)v1.x; afs[s][5] = (bf16_t)v1.y;
                afs[s][6] = (bf16_t)v1.z; afs[s][7] = (bf16_t)v1.w;
            }
        }
#pragma unroll
        for (int s = 0; s < 8; ++s) {
#pragma unroll
            for (int ct = 0; ct < 4; ++ct) {
                const int c = ct * 16 + mrow;
                bf16x8 bfr = *(const bf16x8*)&Vs[kh][c * 256 + (((s * 4 + quad) ^ (c & 7)) * 8)];
                acc[ct] = __builtin_amdgcn_mfma_f32_16x16x32_bf16(afs[s], bfr, acc[ct], 0, 0, 0);
            }
        }
        __syncthreads();            // all waves done reading Vs[*]
        if (stg < 7) {
#pragma unroll
            for (int rr = 0; rr < 8; ++rr) *(uint4*)&Vs[kh][loff[rr]] = brg[rr];
            __syncthreads();        // next stage staged
        }
    }

    // ---- K-half reduce: acc -> Yl ----
#pragma unroll
    for (int ct = 0; ct < 4; ++ct)
#pragma unroll
        for (int r = 0; r < 4; ++r)
            Yl[kh][wr * 16 + quad * 4 + r][ct * 16 + mrow] = acc[ct][r];
    __syncthreads();

    // ---- gates (waves 0-3, one wave per 16 rows) ----
    if (wave < 4) {
        const int rl = wave * 16 + mrow;
        const float* ya = &Yl[0][rl][0];
        const float* yb = &Yl[1][rl][0];
        bf16x8 f0, f1;   // f0 = cols 0..31 (h / h_mid), f1 = cols 32..63 (x / m)
#pragma unroll
        for (int j = 0; j < 8; ++j) {
            f0[j] = (bf16_t)(ya[quad * 8 + j] + yb[quad * 8 + j]);
            f1[j] = (bf16_t)(ya[32 + quad * 8 + j] + yb[32 + quad * 8 + j]);
        }
        constexpr int NGI = G1 ? 4 : 3;
        constexpr int GB  = G1 ? 0 : 8;
        float gate[NGI][2][4];
#pragma unroll
        for (int gi = 0; gi < NGI; ++gi) {
            const int ge = GB + 2 * gi, go = ge + 1;
            f32x4 ze[4], zo[4];
#pragma unroll
            for (int ct = 0; ct < 4; ++ct) {
                bf16x8 we = *(const bf16x8*)&Wf[((ge * 4 + ct) * 64 + lane) * 8];
                bf16x8 wo = *(const bf16x8*)&Wf[((go * 4 + ct) * 64 + lane) * 8];
                // G1: even gate acts on x (f1), odd on h (f0).
                // G2: even gate acts on h_mid (f0), odd on m (f1).
                ze[ct] = __builtin_amdgcn_mfma_f32_16x16x32_bf16(G1 ? f1 : f0, we, zero4, 0, 0, 0);
                zo[ct] = __builtin_amdgcn_mfma_f32_16x16x32_bf16(G1 ? f0 : f1, wo, zero4, 0, 0, 0);
                const float be = bias[ge * 64 + ct * 16 + mrow];
                const float bo = bias[go * 64 + ct * 16 + mrow];
#pragma unroll
                for (int r = 0; r < 4; ++r) { ze[ct][r] += be; zo[ct][r] += bo; }
            }
#pragma unroll
            for (int p = 0; p < 2; ++p)
#pragma unroll
                for (int r = 0; r < 4; ++r) {
                    float s = ze[p][r] * sigm(ze[p + 2][r]) + zo[p][r] * sigm(zo[p + 2][r]);
                    gate[gi][p][r] = (G1 && gi == 2) ? tanh_f(s) : sigm(s);
                }
        }
#pragma unroll
        for (int p = 0; p < 2; ++p)
#pragma unroll
            for (int r = 0; r < 4; ++r) {
                const int rloc = wave * 16 + quad * 4 + r;
                const int rowg = n0 + rloc, col = p * 16 + mrow;
                const size_t ci = ((size_t)b * NN + rowg) * FF + col;
                if constexpr (G1) {
                    float cn = gate[0][p][r] * cm[ci] + gate[1][p][r] * gate[2][p][r];
                    cm[ci] = cn;
                    t0T[col][rloc] = (bf16_t)(gate[3][p][r] * tanh_f(cn));
                } else {
                    const float i2 = gate[0][p][r], gg = gate[1][p][r], o2 = gate[2][p][r];
                    float mn = i2 * cm[ci] + (1.f - i2) * gg;
                    cm[ci] = mn;
                    float hn = mn * o2;
                    hs[(((size_t)b * TT + t) * NN + rowg) * FF + col] = hn;
                    t0T[col][rloc] = (bf16_t)mn;
                    t1T[col][rloc] = (bf16_t)hn;
                }
            }
    }
    __syncthreads();
    // ---- transposed coalesced writes: [b][col][n] bf16 panels ----
    if (tid < 256) {
        const int col = tid >> 3, seg = tid & 7;
        union { uint4 u; bf16_t h[8]; } o0;
#pragma unroll
        for (int j = 0; j < 8; ++j) o0.h[j] = t0T[col][seg * 8 + j];
        *(uint4*)&hmW[((size_t)b * 32 + col) * NN + n0 + seg * 8] = o0.u;
        if constexpr (!G1) {
            union { uint4 u; bf16_t h[8]; } o1;
#pragma unroll
            for (int j = 0; j < 8; ++j) o1.h[j] = t1T[col][seg * 8 + j];
            *(uint4*)&hb[((size_t)b * FF + col) * NN + n0 + seg * 8] = o1.u;
        }
    }
}

// ---------------- tail: last_h / last_c / last_m ----------------------------
__global__ __launch_bounds__(256) void finalize_k(const float* __restrict__ hs,
                                                  const float* __restrict__ c,
                                                  const float* __restrict__ m,
                                                  float* __restrict__ tail) {
    const int idx = blockIdx.x * 256 + threadIdx.x;   // 524288
    const int b = idx >> 17, r = idx & 131071;
    tail[idx] = hs[((size_t)b * TT + (TT - 1)) * 131072 + r];
    tail[524288 + idx] = c[idx];
    tail[1048576 + idx] = m[idx];
}

// ---------------------------------------------------------------------------
extern "C" void kernel_launch(void* const* d_in, const int* in_sizes, int n_in,
                              void* d_out, int out_size, void* d_ws, size_t ws_size,
                              hipStream_t stream) {
    const float* x    = (const float*)d_in[0];   // [4,12,4096,32]
    const float* adj  = (const float*)d_in[1];   // [4,4096,4096]
    const float* W    = (const float*)d_in[2];   // [14,32,64]
    const float* bias = (const float*)d_in[3];   // [14,64]
    float* out = (float*)d_out;

    char* ws = (char*)d_ws;
    size_t off = 0;
    auto carve = [&](size_t bytes) -> void* {
        void* p = ws + off;
        off += (bytes + 255) & ~(size_t)255;
        return p;
    };
    bf16_t* xT    = (bf16_t*)carve((size_t)BB * 384 * NN * 2);   // 12.6 MB
    bf16_t* h_bf  = (bf16_t*)carve((size_t)BB * 32 * NN * 2);    // 1 MB
    bf16_t* hmid  = (bf16_t*)carve((size_t)BB * 32 * NN * 2);    // 1 MB
    bf16_t* mbf0  = (bf16_t*)carve((size_t)BB * 32 * NN * 2);    // 1 MB
    bf16_t* mbf1  = (bf16_t*)carve((size_t)BB * 32 * NN * 2);    // 1 MB
    bf16_t* Wf    = (bf16_t*)carve((size_t)14 * 4 * 64 * 8 * 2);
    float*  cbuf  = (float*)carve((size_t)BB * NN * FF * 4);     // 2 MB
    float*  mbuf  = (float*)carve((size_t)BB * NN * FF * 4);     // 2 MB
    const size_t adj_bytes = (size_t)BB * NN * NN * 2;           // 134 MB
    const bool abf = (ws_size >= off + adj_bytes);
    bf16_t* adj_bf = abf ? (bf16_t*)carve(adj_bytes) : nullptr;

    if (abf) conv_adj_k<<<32768, 256, 0, stream>>>(adj, adj_bf);
    make_wfrag_k<<<14, 256, 0, stream>>>(W, Wf);
    xpose_k<<<dim3(64, TT, BB), 256, 0, stream>>>(x, xT);
    init_k<<<2048, 256, 0, stream>>>(h_bf, mbf0, cbuf, mbuf);

    const dim3 grid(64, BB);
    for (int t = 0; t < TT; ++t) {
        const bf16_t* xts = xT + (size_t)t * 32 * NN;
        bf16_t* mrd = (t & 1) ? mbf1 : mbf0;
        bf16_t* mwr = (t & 1) ? mbf0 : mbf1;
        if (abf) {
            gg_k<true,  true ><<<grid, 512, 0, stream>>>(adj_bf, h_bf, xts, Wf, bias,
                                                         cbuf, hmid, nullptr, nullptr, 0);
            gg_k<true,  false><<<grid, 512, 0, stream>>>(adj_bf, hmid, mrd, Wf, bias,
                                                         mbuf, mwr, h_bf, out, t);
        } else {
            gg_k<false, true ><<<grid, 512, 0, stream>>>(adj, h_bf, xts, Wf, bias,
                                                         cbuf, hmid, nullptr, nullptr, 0);
            gg_k<false, false><<<grid, 512, 0, stream>>>(adj, hmid, mrd, Wf, bias,
                                                         mbuf, mwr, h_bf, out, t);
        }
    }
    finalize_k<<<2048, 256, 0, stream>>>(out, cbuf, mbuf, out + (size_t)BB * TT * NN * FF);
}